// Round 3
// baseline (403.956 us; speedup 1.0000x reference)
//
#include <hip/hip_runtime.h>

// DotProductAttention: B=16, NQ=2048, NK=2048, D=128, DV=128, fp32 in/out.
// Flash-attention, bf16 MFMA 16x16x32, online softmax, valid_len early-exit.
// R3: split-K x2 (1024 blocks -> HW dynamic balance), last-finisher merge via
// d_ws flags (write->fence->atomic, no spin), 3 blocks/CU, v_cvt_pk_bf16_f32.

#define B_   16
#define NQ_  2048
#define NK_  2048
#define D_   128
#define DV_  128
#define NQT_ 32            // q-tiles of 64 rows
#define NPAIR_ (B_ * NQT_) // 512 (b, qtile) pairs
#define KHALF_TILES 16     // 1024 keys per K-half

typedef __attribute__((ext_vector_type(4))) float          f32x4;
typedef __attribute__((ext_vector_type(8))) __bf16         bf16x8;
typedef __attribute__((ext_vector_type(8))) unsigned short ushort8v;
typedef __attribute__((ext_vector_type(2))) unsigned int   uint2v;
typedef __attribute__((ext_vector_type(4))) unsigned int   uint4v;

#ifdef __has_builtin
#if __has_builtin(__builtin_amdgcn_cvt_pk_bf16_f32)
#define HAVE_CVT_PK_BF16 1
#endif
#endif

// fp32 -> bf16 round-half-up (inputs are normal randoms, no NaN)
__device__ __forceinline__ unsigned short f2bf(float f) {
    unsigned u = __builtin_bit_cast(unsigned, f);
    return (unsigned short)((u + 0x8000u) >> 16);
}
__device__ __forceinline__ float bf2f(unsigned short h) {
    unsigned u = ((unsigned)h) << 16;
    return __builtin_bit_cast(float, u);
}
// pack two fp32 -> two bf16 in one dword (low = a, high = b)
__device__ __forceinline__ unsigned f2bf2(float a, float b) {
#ifdef HAVE_CVT_PK_BF16
    auto t = __builtin_amdgcn_cvt_pk_bf16_f32(a, b);
    return __builtin_bit_cast(unsigned, t);
#else
    return (unsigned)f2bf(a) | ((unsigned)f2bf(b) << 16);
#endif
}

__global__ void init_flags(int* __restrict__ f) { f[threadIdx.x] = 0; }

__global__ __launch_bounds__(256, 3) void attn_fwd(
    const float* __restrict__ Q, const float* __restrict__ K,
    const float* __restrict__ V, const int* __restrict__ vlen,
    float* __restrict__ Out, int* __restrict__ flags,
    float* __restrict__ mlbuf, unsigned short* __restrict__ obuf)
{
    // K-tile rows: 64 keys x 128 d, stride 136 ushorts (17*16B)
    __shared__ unsigned short Kt[64][136];
    // V^T: 128 dv x 64 keys, XOR-swizzled 16B units: (dv,key) at dv*64+((key>>3)^(dv&7))*8+(key&7)
    __shared__ unsigned short Vt[128 * 64];
    // per-wave P buffer: 16 q x 64 keys, stride 72
    __shared__ unsigned short Pb[4][16][72];
    __shared__ int s_old;

    const int tid  = threadIdx.x;
    const int w    = tid >> 6;
    const int L    = tid & 63;
    const int col  = L & 15;
    const int quad = L >> 4;

    const int id   = blockIdx.x;          // 0..1023
    const int h    = id >> 9;             // K-half 0/1
    const int pid  = id & 511;            // (b, qtile) pair
    const int b    = pid & 15;            // batch inner -> resident blocks span batches
    const int qt   = pid >> 4;
    const int qbase = qt * 64;
    const int vl    = vlen[b];
    const int ntiles = (vl + 63) >> 6;
    const int t0 = h * KHALF_TILES;
    const int t1 = ntiles < (h + 1) * KHALF_TILES ? ntiles : (h + 1) * KHALF_TILES;

    f32x4 o[8];
    #pragma unroll
    for (int c = 0; c < 8; ++c) o[c] = (f32x4){0.f, 0.f, 0.f, 0.f};
    float m_run[4] = {-1e30f, -1e30f, -1e30f, -1e30f};
    float l_run[4] = {0.f, 0.f, 0.f, 0.f};

    if (t0 < t1) {   // uniform per block
        // ---- Q fragments (A-layout), pre-scaled by log2(e)/sqrt(128)
        const float qscale = 0.12751743f;
        bf16x8 qf[4];
        {
            const int qrow = qbase + w * 16 + col;
            const float* gQ = Q + ((size_t)b * NQ_ + qrow) * D_;
            #pragma unroll
            for (int c = 0; c < 4; ++c) {
                const float* p = gQ + c * 32 + quad * 8;
                f32x4 a0 = *(const f32x4*)(p);
                f32x4 a1 = *(const f32x4*)(p + 4);
                uint4v us;
                us[0] = f2bf2(a0[0] * qscale, a0[1] * qscale);
                us[1] = f2bf2(a0[2] * qscale, a0[3] * qscale);
                us[2] = f2bf2(a1[0] * qscale, a1[1] * qscale);
                us[3] = f2bf2(a1[2] * qscale, a1[3] * qscale);
                qf[c] = __builtin_bit_cast(bf16x8, us);
            }
        }

        const float* gKb = K + (size_t)b * NK_ * D_;
        const float* gVb = V + (size_t)b * NK_ * DV_;

        f32x4 kreg[8];     // K: 8 x (1 key-row, 4 d)
        float vreg[4][8];  // V: 4 x (1 dv, 8 keys)

        #define ISSUE_LOADS(K0)                                                  \
            do {                                                                 \
                _Pragma("unroll")                                                \
                for (int i = 0; i < 8; ++i) {                                    \
                    int f = i * 256 + tid;                                       \
                    int row = f >> 5, c4 = (f & 31) * 4;                         \
                    kreg[i] = *(const f32x4*)(gKb + (size_t)((K0) + row) * D_ + c4); \
                }                                                                \
                _Pragma("unroll")                                                \
                for (int i = 0; i < 4; ++i) {                                    \
                    int item = i * 256 + tid;                                    \
                    int dv = item & 127, kg = item >> 7;                         \
                    const float* vp = gVb + (size_t)((K0) + kg * 8) * DV_ + dv;  \
                    _Pragma("unroll")                                            \
                    for (int j = 0; j < 8; ++j) vreg[i][j] = vp[(size_t)j * DV_];\
                }                                                                \
            } while (0)

        ISSUE_LOADS(t0 * 64);

        for (int kt = t0; kt < t1; ++kt) {
            __syncthreads();

            // ---- stage registers to LDS as bf16
            #pragma unroll
            for (int i = 0; i < 8; ++i) {
                int f = i * 256 + tid;
                int row = f >> 5, c4 = (f & 31) * 4;
                uint2v ks;
                ks[0] = f2bf2(kreg[i][0], kreg[i][1]);
                ks[1] = f2bf2(kreg[i][2], kreg[i][3]);
                *(uint2v*)&Kt[row][c4] = ks;
            }
            #pragma unroll
            for (int i = 0; i < 4; ++i) {
                int item = i * 256 + tid;
                int dv = item & 127, kg = item >> 7;
                uint4v us;
                us[0] = f2bf2(vreg[i][0], vreg[i][1]);
                us[1] = f2bf2(vreg[i][2], vreg[i][3]);
                us[2] = f2bf2(vreg[i][4], vreg[i][5]);
                us[3] = f2bf2(vreg[i][6], vreg[i][7]);
                *(uint4v*)&Vt[dv * 64 + ((kg ^ (dv & 7)) << 3)] = us;
            }

            if (kt + 1 < t1) ISSUE_LOADS((kt + 1) * 64);

            __syncthreads();

            const int k0 = kt * 64;

            // ---- S = Q K^T (log2 domain)
            f32x4 s[4];
            #pragma unroll
            for (int kc = 0; kc < 4; ++kc) {
                f32x4 acc = (f32x4){0.f, 0.f, 0.f, 0.f};
                const unsigned short* krow = &Kt[kc * 16 + col][quad * 8];
                #pragma unroll
                for (int c = 0; c < 4; ++c) {
                    bf16x8 kb = __builtin_bit_cast(bf16x8, *(const ushort8v*)(krow + c * 32));
                    acc = __builtin_amdgcn_mfma_f32_16x16x32_bf16(qf[c], kb, acc, 0, 0, 0);
                }
                s[kc] = acc;
            }

            // ---- mask (only a partial last tile)
            if (k0 + 64 > vl) {
                #pragma unroll
                for (int kc = 0; kc < 4; ++kc)
                    if (k0 + kc * 16 + col >= vl)
                        s[kc] = (f32x4){-1e30f, -1e30f, -1e30f, -1e30f};
            }

            // ---- online softmax
            float mx[4];
            #pragma unroll
            for (int r = 0; r < 4; ++r)
                mx[r] = fmaxf(fmaxf(s[0][r], s[1][r]), fmaxf(s[2][r], s[3][r]));
            #pragma unroll
            for (int off = 1; off < 16; off <<= 1) {
                #pragma unroll
                for (int r = 0; r < 4; ++r)
                    mx[r] = fmaxf(mx[r], __shfl_xor(mx[r], off, 64));
            }

            f32x4 al;
            #pragma unroll
            for (int r = 0; r < 4; ++r) {
                float mn = fmaxf(m_run[r], mx[r]);
                al[r] = exp2f(m_run[r] - mn);
                m_run[r] = mn;
            }

            float rs[4] = {0.f, 0.f, 0.f, 0.f};
            #pragma unroll
            for (int kc = 0; kc < 4; ++kc) {
                #pragma unroll
                for (int r = 0; r < 4; ++r) {
                    unsigned short pb = f2bf(exp2f(s[kc][r] - m_run[r]));
                    Pb[w][quad * 4 + r][kc * 16 + col] = pb;
                    rs[r] += bf2f(pb);
                }
            }
            #pragma unroll
            for (int off = 1; off < 16; off <<= 1) {
                #pragma unroll
                for (int r = 0; r < 4; ++r)
                    rs[r] += __shfl_xor(rs[r], off, 64);
            }
            #pragma unroll
            for (int r = 0; r < 4; ++r)
                l_run[r] = l_run[r] * al[r] + rs[r];
            #pragma unroll
            for (int c = 0; c < 8; ++c) o[c] *= al;

            // Pb[w] is per-wave: no barrier needed (in-order DS per wave)

            // ---- O += P V
            #pragma unroll
            for (int kc2 = 0; kc2 < 2; ++kc2) {
                bf16x8 pa = __builtin_bit_cast(bf16x8,
                    *(const ushort8v*)&Pb[w][col][kc2 * 32 + quad * 8]);
                #pragma unroll
                for (int c = 0; c < 8; ++c) {
                    int dv = c * 16 + col;
                    int sw = ((kc2 * 4 + quad) ^ (col & 7)) << 3;
                    bf16x8 vb = __builtin_bit_cast(bf16x8,
                        *(const ushort8v*)&Vt[dv * 64 + sw]);
                    o[c] = __builtin_amdgcn_mfma_f32_16x16x32_bf16(pa, vb, o[c], 0, 0, 0);
                }
            }
        }
        #undef ISSUE_LOADS
    }

    // ---- write partial (m, l fp32; unnormalized O bf16) to ws
    const int slot = pid * 2 + h;
    const int myrow = w * 16 + quad * 4;     // + r
    float* ml = mlbuf + (size_t)slot * 128;
    if (col == 0) {
        #pragma unroll
        for (int r = 0; r < 4; ++r) {
            ml[myrow + r]      = m_run[r];
            ml[64 + myrow + r] = l_run[r];
        }
    }
    if (t0 < t1) {
        unsigned short* Ow = obuf + (size_t)slot * 8192;
        #pragma unroll
        for (int c = 0; c < 8; ++c)
            #pragma unroll
            for (int r = 0; r < 4; ++r)
                Ow[(size_t)(myrow + r) * 128 + c * 16 + col] = f2bf(o[c][r]);
    }
    __threadfence();       // release: my writes before the flag bump
    __syncthreads();       // whole block's writes done
    if (tid == 0) s_old = atomicAdd(&flags[pid], 1);
    __syncthreads();

    if (s_old == 1) {      // last finisher: merge partner partial, store final
        __threadfence();   // acquire
        const int oslot = pid * 2 + (1 - h);
        const float* mlo = mlbuf + (size_t)oslot * 128;
        const unsigned short* Oo = obuf + (size_t)oslot * 8192;
        float aa[4], ab[4], inv[4];
        #pragma unroll
        for (int r = 0; r < 4; ++r) {
            float mb = mlo[myrow + r];
            float lb = mlo[64 + myrow + r];
            float m  = fmaxf(m_run[r], mb);
            aa[r] = exp2f(m_run[r] - m);   // exactly 0 if own half empty
            ab[r] = exp2f(mb - m);         // exactly 0 if partner empty
            inv[r] = 1.0f / (l_run[r] * aa[r] + lb * ab[r]);
        }
        float* gO = Out + ((size_t)b * NQ_ + qbase + w * 16) * DV_;
        #pragma unroll
        for (int c = 0; c < 8; ++c) {
            #pragma unroll
            for (int r = 0; r < 4; ++r) {
                float pv = bf2f(Oo[(size_t)(myrow + r - w * 16 + w * 16) * 128 + c * 16 + col]);
                gO[(size_t)(quad * 4 + r) * DV_ + c * 16 + col] =
                    (o[c][r] * aa[r] + pv * ab[r]) * inv[r];
            }
        }
    }
}

extern "C" void kernel_launch(void* const* d_in, const int* in_sizes, int n_in,
                              void* d_out, int out_size, void* d_ws, size_t ws_size,
                              hipStream_t stream) {
    const float* Q  = (const float*)d_in[0];
    const float* K  = (const float*)d_in[1];
    const float* V  = (const float*)d_in[2];
    const int*   vl = (const int*)d_in[3];
    float* out = (float*)d_out;

    // ws layout: [0,2048) flags | [4096, 4096+512K) ml | [1MB, 1MB+16MB) O partials
    char* ws = (char*)d_ws;
    int*   flags = (int*)ws;
    float* mlbuf = (float*)(ws + 4096);
    unsigned short* obuf = (unsigned short*)(ws + (1u << 20));
    // requires ws_size >= 17 MB

    init_flags<<<1, NPAIR_, 0, stream>>>(flags);
    attn_fwd<<<dim3(2 * NPAIR_, 1, 1), dim3(256, 1, 1), 0, stream>>>(
        Q, K, V, vl, out, flags, mlbuf, obuf);
}

// Round 4
// 158.565 us; speedup vs baseline: 2.5476x; 2.5476x over previous
//
#include <hip/hip_runtime.h>

// DotProductAttention: B=16, NQ=2048, NK=2048, D=128, DV=128, fp32 in/out.
// Flash-attention, bf16 MFMA 16x16x32, online softmax, valid_len early-exit.
// R4: revert to R2 structure (no split-K / no per-block fences — R3 showed
// agent-scope fences + merge cost 4x). Add: (a) complementary batch pairing
// via tiny scheduler kernel (blocks id and id+256 share a CU under the
// round-robin-XCD dispatch model; pair longest vl with shortest), (b) packed
// f32->bf16x2 conversion in staging.

#define B_   16
#define NQ_  2048
#define NK_  2048
#define D_   128
#define DV_  128
#define NTASK_ 512   // 16 batches x 32 q-tiles

typedef __attribute__((ext_vector_type(4))) float          f32x4;
typedef __attribute__((ext_vector_type(8))) __bf16         bf16x8;
typedef __attribute__((ext_vector_type(8))) unsigned short ushort8v;
typedef __attribute__((ext_vector_type(2))) unsigned int   uint2v;
typedef __attribute__((ext_vector_type(4))) unsigned int   uint4v;

#ifdef __has_builtin
#if __has_builtin(__builtin_amdgcn_cvt_pk_bf16_f32)
#define HAVE_CVT_PK_BF16 1
#endif
#endif

// fp32 -> bf16 round-half-up (inputs are normal randoms, no NaN)
__device__ __forceinline__ unsigned short f2bf(float f) {
    unsigned u = __builtin_bit_cast(unsigned, f);
    return (unsigned short)((u + 0x8000u) >> 16);
}
__device__ __forceinline__ float bf2f(unsigned short h) {
    unsigned u = ((unsigned)h) << 16;
    return __builtin_bit_cast(float, u);
}
// pack two fp32 -> two bf16 in one dword (low = a, high = b)
__device__ __forceinline__ unsigned f2bf2(float a, float b) {
#ifdef HAVE_CVT_PK_BF16
    auto t = __builtin_amdgcn_cvt_pk_bf16_f32(a, b);
    return __builtin_bit_cast(unsigned, t);
#else
    return (unsigned)f2bf(a) | ((unsigned)f2bf(b) << 16);
#endif
}

// Build the task table: rank batches by vl desc, pair s[p] with s[15-p] so
// co-resident blocks (id, id+256) get complementary work. task = b | (qt<<8).
__global__ void make_schedule(const int* __restrict__ vlen, int* __restrict__ task) {
    __shared__ int s[16];
    int tid = threadIdx.x;            // 64 threads
    if (tid < 16) {
        int my = vlen[tid];
        int rank = 0;
        for (int o = 0; o < 16; ++o) {
            int vo = vlen[o];
            if (vo > my || (vo == my && o < tid)) ++rank;
        }
        s[rank] = tid;
    }
    __syncthreads();
    for (int e = tid; e < NTASK_; e += 64) {
        int half = e >> 8;            // 0: first CU slot, 1: partner slot
        int r    = e & 255;
        int p    = r >> 5;            // batch-pair index 0..7
        int qt   = r & 31;
        int b    = half ? s[15 - p] : s[p];
        task[e]  = b | (qt << 8);
    }
}

__global__ __launch_bounds__(256, 2) void attn_fwd(
    const float* __restrict__ Q, const float* __restrict__ K,
    const float* __restrict__ V, const int* __restrict__ vlen,
    const int* __restrict__ task, float* __restrict__ Out)
{
    // K-tile rows: 64 keys x 128 d, stride 136 ushorts (17*16B: b128 reads 2-way free)
    __shared__ unsigned short Kt[64][136];
    // V^T: 128 dv rows x 64 keys, flat, XOR-swizzled at 16B-unit granularity:
    //   element (dv, key) lives at dv*64 + ((key>>3) ^ (dv&7))*8 + (key&7)
    __shared__ unsigned short Vt[128 * 64];
    // per-wave P buffer: 16 q x 64 keys, stride 72 (9*16B)
    __shared__ unsigned short Pb[4][16][72];

    const int tid  = threadIdx.x;
    const int w    = tid >> 6;    // wave id 0..3
    const int L    = tid & 63;    // lane
    const int col  = L & 15;      // MFMA n/col & A-row index
    const int quad = L >> 4;      // MFMA quad

    const int tk    = task[blockIdx.x];
    const int b     = tk & 255;
    const int qbase = (tk >> 8) * 64;
    const int vl    = vlen[b];
    const int ntiles = (vl + 63) >> 6;   // tiles fully past vl contribute exactly 0

    // ---- Q fragments (A-layout: A[m=col][k=quad*8+j]), pre-scaled by log2(e)/sqrt(128)
    const float qscale = 0.12751743f;
    bf16x8 qf[4];
    {
        const int qrow = qbase + w * 16 + col;
        const float* gQ = Q + ((size_t)b * NQ_ + qrow) * D_;
        #pragma unroll
        for (int c = 0; c < 4; ++c) {
            const float* p = gQ + c * 32 + quad * 8;
            f32x4 a0 = *(const f32x4*)(p);
            f32x4 a1 = *(const f32x4*)(p + 4);
            uint4v us;
            us[0] = f2bf2(a0[0] * qscale, a0[1] * qscale);
            us[1] = f2bf2(a0[2] * qscale, a0[3] * qscale);
            us[2] = f2bf2(a1[0] * qscale, a1[1] * qscale);
            us[3] = f2bf2(a1[2] * qscale, a1[3] * qscale);
            qf[c] = __builtin_bit_cast(bf16x8, us);
        }
    }

    // ---- accumulators (C-layout: row = quad*4 + r, col = dv chunk*16 + col)
    f32x4 o[8];
    #pragma unroll
    for (int c = 0; c < 8; ++c) o[c] = (f32x4){0.f, 0.f, 0.f, 0.f};
    float m_run[4] = {-1e30f, -1e30f, -1e30f, -1e30f};
    float l_run[4] = {0.f, 0.f, 0.f, 0.f};

    const float* gKb = K + (size_t)b * NK_ * D_;
    const float* gVb = V + (size_t)b * NK_ * DV_;

    // ---- prefetch registers: raw fp32 for next tile (convert at write time)
    f32x4 kreg[8];        // K: 8 iters x (1 key-row, 4 d)
    float vreg[4][8];     // V: 4 iters x (1 dv, 8 keys)

    #define ISSUE_LOADS(K0)                                                  \
        do {                                                                 \
            _Pragma("unroll")                                                \
            for (int i = 0; i < 8; ++i) {                                    \
                int f = i * 256 + tid;                                       \
                int row = f >> 5, c4 = (f & 31) * 4;                         \
                kreg[i] = *(const f32x4*)(gKb + (size_t)((K0) + row) * D_ + c4); \
            }                                                                \
            _Pragma("unroll")                                                \
            for (int i = 0; i < 4; ++i) {                                    \
                int item = i * 256 + tid;                                    \
                int dv = item & 127, kg = item >> 7;                         \
                const float* vp = gVb + (size_t)((K0) + kg * 8) * DV_ + dv;  \
                _Pragma("unroll")                                            \
                for (int j = 0; j < 8; ++j) vreg[i][j] = vp[(size_t)j * DV_];\
            }                                                                \
        } while (0)

    ISSUE_LOADS(0);

    for (int kt = 0; kt < ntiles; ++kt) {
        __syncthreads();   // all waves done reading previous tile's LDS

        // ---- write staged registers to LDS (bf16)
        #pragma unroll
        for (int i = 0; i < 8; ++i) {
            int f = i * 256 + tid;
            int row = f >> 5, c4 = (f & 31) * 4;
            uint2v ks;
            ks[0] = f2bf2(kreg[i][0], kreg[i][1]);
            ks[1] = f2bf2(kreg[i][2], kreg[i][3]);
            *(uint2v*)&Kt[row][c4] = ks;   // b64
        }
        #pragma unroll
        for (int i = 0; i < 4; ++i) {
            int item = i * 256 + tid;
            int dv = item & 127, kg = item >> 7;
            uint4v us;
            us[0] = f2bf2(vreg[i][0], vreg[i][1]);
            us[1] = f2bf2(vreg[i][2], vreg[i][3]);
            us[2] = f2bf2(vreg[i][4], vreg[i][5]);
            us[3] = f2bf2(vreg[i][6], vreg[i][7]);
            *(uint4v*)&Vt[dv * 64 + ((kg ^ (dv & 7)) << 3)] = us;  // b128, swizzled
        }

        // ---- issue next tile's global loads (overlap with compute below)
        if (kt + 1 < ntiles) ISSUE_LOADS((kt + 1) * 64);

        __syncthreads();   // staged tile visible

        const int k0 = kt * 64;

        // ---- S-tile = Q K^T (log2 domain; 16 q x 64 keys per wave)
        f32x4 s[4];
        #pragma unroll
        for (int kc = 0; kc < 4; ++kc) {
            f32x4 acc = (f32x4){0.f, 0.f, 0.f, 0.f};
            const unsigned short* krow = &Kt[kc * 16 + col][quad * 8];
            #pragma unroll
            for (int c = 0; c < 4; ++c) {
                bf16x8 kb = __builtin_bit_cast(bf16x8, *(const ushort8v*)(krow + c * 32));
                acc = __builtin_amdgcn_mfma_f32_16x16x32_bf16(qf[c], kb, acc, 0, 0, 0);
            }
            s[kc] = acc;
        }

        // ---- mask (only the last tile can be partial)
        if (k0 + 64 > vl) {
            #pragma unroll
            for (int kc = 0; kc < 4; ++kc)
                if (k0 + kc * 16 + col >= vl)
                    s[kc] = (f32x4){-1e30f, -1e30f, -1e30f, -1e30f};
        }

        // ---- online softmax: row max over 16 lanes sharing each q row
        float mx[4];
        #pragma unroll
        for (int r = 0; r < 4; ++r)
            mx[r] = fmaxf(fmaxf(s[0][r], s[1][r]), fmaxf(s[2][r], s[3][r]));
        #pragma unroll
        for (int off = 1; off < 16; off <<= 1) {
            #pragma unroll
            for (int r = 0; r < 4; ++r)
                mx[r] = fmaxf(mx[r], __shfl_xor(mx[r], off, 64));
        }

        f32x4 al;
        #pragma unroll
        for (int r = 0; r < 4; ++r) {
            float mn = fmaxf(m_run[r], mx[r]);
            al[r] = exp2f(m_run[r] - mn);
            m_run[r] = mn;
        }

        // ---- p = exp2(s - m), write P (bf16) to per-wave LDS, sum rounded p
        float rs[4] = {0.f, 0.f, 0.f, 0.f};
        #pragma unroll
        for (int kc = 0; kc < 4; ++kc) {
            #pragma unroll
            for (int r = 0; r < 4; ++r) {
                unsigned short pb = f2bf(exp2f(s[kc][r] - m_run[r]));
                Pb[w][quad * 4 + r][kc * 16 + col] = pb;
                rs[r] += bf2f(pb);
            }
        }
        #pragma unroll
        for (int off = 1; off < 16; off <<= 1) {
            #pragma unroll
            for (int r = 0; r < 4; ++r)
                rs[r] += __shfl_xor(rs[r], off, 64);
        }
        #pragma unroll
        for (int r = 0; r < 4; ++r)
            l_run[r] = l_run[r] * al[r] + rs[r];
        #pragma unroll
        for (int c = 0; c < 8; ++c) o[c] *= al;

        // Pb[w] is per-wave: no barrier needed (in-order DS per wave)

        // ---- O += P V  (A = P[q=col][key=quad*8+j], B = V^T swizzled)
        #pragma unroll
        for (int kc2 = 0; kc2 < 2; ++kc2) {
            bf16x8 pa = __builtin_bit_cast(bf16x8,
                *(const ushort8v*)&Pb[w][col][kc2 * 32 + quad * 8]);
            #pragma unroll
            for (int c = 0; c < 8; ++c) {
                int dv = c * 16 + col;
                int sw = ((kc2 * 4 + quad) ^ (col & 7)) << 3;
                bf16x8 vb = __builtin_bit_cast(bf16x8,
                    *(const ushort8v*)&Vt[dv * 64 + sw]);
                o[c] = __builtin_amdgcn_mfma_f32_16x16x32_bf16(pa, vb, o[c], 0, 0, 0);
            }
        }
    }

    // ---- normalize and store
    f32x4 linv;
    #pragma unroll
    for (int r = 0; r < 4; ++r) linv[r] = 1.0f / l_run[r];
    float* gO = Out + ((size_t)b * NQ_ + qbase + w * 16) * DV_;
    #pragma unroll
    for (int c = 0; c < 8; ++c) {
        #pragma unroll
        for (int r = 0; r < 4; ++r)
            gO[(size_t)(quad * 4 + r) * DV_ + c * 16 + col] = o[c][r] * linv[r];
    }
    #undef ISSUE_LOADS
}

extern "C" void kernel_launch(void* const* d_in, const int* in_sizes, int n_in,
                              void* d_out, int out_size, void* d_ws, size_t ws_size,
                              hipStream_t stream) {
    const float* Q  = (const float*)d_in[0];
    const float* K  = (const float*)d_in[1];
    const float* V  = (const float*)d_in[2];
    const int*   vl = (const int*)d_in[3];
    float* out = (float*)d_out;
    int* task = (int*)d_ws;   // NTASK_ ints

    make_schedule<<<1, 64, 0, stream>>>(vl, task);
    attn_fwd<<<dim3(NTASK_, 1, 1), dim3(256, 1, 1), 0, stream>>>(
        Q, K, V, vl, task, out);
}